// Round 15
// baseline (395.383 us; speedup 1.0000x reference)
//
#include <hip/hip_runtime.h>
#include <hip/hip_bf16.h>

#define NNODES 50000
#define NEDGES 800000
#define DIM 128
#define NH 8
#define HID 512
#define NB 196               // scan blocks: ceil(50000/256)
#define CVT_BLOCKS 1344
#define DEG_BLOCKS 3125      // ceil(800000/256)

typedef unsigned short ushort_t;
typedef unsigned int uint_t;
typedef __attribute__((ext_vector_type(8))) short bf16x8;
typedef __attribute__((ext_vector_type(4))) float f32x4;
typedef __attribute__((ext_vector_type(4))) uint_t u32x4;   // nt-capable uint4

__device__ __forceinline__ ushort_t f2bf_bits(float v) {
    __hip_bfloat16 b = __float2bfloat16(v);
    return *(ushort_t*)&b;
}

// ---------------------------------------------------------------------------
// r24: convert weights + attn-composite + degree_count in ONE dispatch
// (independent work partitioned by blockIdx; degree blocks are >= CVT_BLOCKS).
// Composite (r19, verified): su = x @ (au_w@fc_w)^T + (au_b + au_w.fc_b),
// sv = x @ (av_w@fc_w)^T + (av_w.fc_b).
// ---------------------------------------------------------------------------
__global__ __launch_bounds__(256) void convert_deg_kernel(
    const float* __restrict__ fc_w, const float* __restrict__ fc_b,
    const float* __restrict__ au_w, const float* __restrict__ au_b,
    const float* __restrict__ av_w,
    const float* __restrict__ w1, const float* __restrict__ w2,
    const int* __restrict__ src, const int* __restrict__ dst,
    ushort_t* __restrict__ fc_wb, ushort_t* __restrict__ w1b,
    ushort_t* __restrict__ w2b,
    ushort_t* __restrict__ afc, float* __restrict__ abc,
    float* __restrict__ out_deg, int* __restrict__ in_cnt, int E)
{
    const int b = blockIdx.x;
    if (b >= CVT_BLOCKS) {
        int e = (b - CVT_BLOCKS) * 256 + threadIdx.x;
        if (e < E) {
            unsafeAtomicAdd(&out_deg[src[e]], 1.f);
            atomicAdd(&in_cnt[dst[e]], 1);
        }
        return;
    }

    int i = b * 256 + threadIdx.x;
    if (i < 16384)
        ((__hip_bfloat16*)fc_wb)[i] = __float2bfloat16(fc_w[i]);
    else if (i < 278528)
        ((__hip_bfloat16*)w1b)[i - 16384] = __float2bfloat16(w1[i - 16384]);
    else if (i < 344064)
        ((__hip_bfloat16*)w2b)[i - 278528] = __float2bfloat16(w2[i - 278528]);

    if (i < 2048) {
        int row = i >> 7, col = i & 127;
        const float* wrow = (row < 8) ? (au_w + row * DIM) : (av_w + (row - 8) * DIM);
        float s = 0.f;
        for (int j = 0; j < DIM; ++j) s += wrow[j] * fc_w[j * DIM + col];
        afc[row * DIM + col] = f2bf_bits(s);
    }
    if (i < 16) {
        const float* wrow = (i < 8) ? (au_w + i * DIM) : (av_w + (i - 8) * DIM);
        float s = (i < 8) ? au_b[i] : 0.f;
        for (int j = 0; j < DIM; ++j) s += wrow[j] * fc_b[j];
        abc[i] = s;
    }
}

// ---------------------------------------------------------------------------
// Fused fc + attn-scores (r19, verified): barrier-free main loop; fc_wb +
// composite afc staged in LDS once; each wave owns a 16-row tile, 9 MFMAs
// per K-step. r25: x loads nontemporal via ext_vector f32x4 (25.6MB
// streamed once -> don't pollute L2; hb/su/sv writes stay cached for
// gather's random re-reads).
// ---------------------------------------------------------------------------
__global__ __launch_bounds__(256, 4) void fc_attn_kernel(
    const float* __restrict__ x,
    const ushort_t* __restrict__ fc_wb, const float* __restrict__ fc_b,
    const ushort_t* __restrict__ afc, const float* __restrict__ abc,
    ushort_t* __restrict__ hb, float* __restrict__ su, float* __restrict__ sv,
    int M)
{
    constexpr int PAD = 8;
    __shared__ ushort_t Ws[128][128 + PAD];   // fc weights, [n][k]  34.8 KB
    __shared__ ushort_t Aw[16][128 + PAD];    // composite [au;av]    4.4 KB

    const int t    = threadIdx.x;
    const int wid  = t >> 6, lane = t & 63;
    const int qd   = lane >> 4, l16 = lane & 15;

#pragma unroll
    for (int i = 0; i < 8; ++i) {
        int v = t + i * 256;               // 0..2047
        int row = v >> 4, ch = v & 15;
        *(uint4*)(&Ws[row][ch * 8]) = *(const uint4*)(fc_wb + row * 128 + ch * 8);
    }
    {
        int row = t >> 4, ch = t & 15;
        *(uint4*)(&Aw[row][ch * 8]) = *(const uint4*)(afc + row * 128 + ch * 8);
    }
    __syncthreads();

    const int tile = blockIdx.x * 4 + wid;
    if (tile * 16 >= M) return;

    const int arow = tile * 16 + l16;
    const float* xp = x + (size_t)arow * DIM + qd * 8;
    const float cb = abc[l16];

    f32x4 acc[8], accs;
#pragma unroll
    for (int i = 0; i < 8; ++i) acc[i] = (f32x4){0.f, 0.f, 0.f, 0.f};
    accs = (f32x4){0.f, 0.f, 0.f, 0.f};

#pragma unroll
    for (int ks = 0; ks < 4; ++ks) {
        f32x4 f0 = __builtin_nontemporal_load((const f32x4*)(xp + ks * 32));
        f32x4 f1 = __builtin_nontemporal_load((const f32x4*)(xp + ks * 32 + 4));
        union { ushort_t u[8]; bf16x8 v; } a;
        a.u[0] = f2bf_bits(f0.x); a.u[1] = f2bf_bits(f0.y);
        a.u[2] = f2bf_bits(f0.z); a.u[3] = f2bf_bits(f0.w);
        a.u[4] = f2bf_bits(f1.x); a.u[5] = f2bf_bits(f1.y);
        a.u[6] = f2bf_bits(f1.z); a.u[7] = f2bf_bits(f1.w);
#pragma unroll
        for (int nf = 0; nf < 8; ++nf) {
            bf16x8 bw = *(const bf16x8*)(&Ws[nf * 16 + l16][ks * 32 + qd * 8]);
            acc[nf] = __builtin_amdgcn_mfma_f32_16x16x32_bf16(a.v, bw, acc[nf], 0, 0, 0);
        }
        bf16x8 ba = *(const bf16x8*)(&Aw[l16][ks * 32 + qd * 8]);
        accs = __builtin_amdgcn_mfma_f32_16x16x32_bf16(a.v, ba, accs, 0, 0, 0);
    }

#pragma unroll
    for (int r = 0; r < 4; ++r) {
        int grow = tile * 16 + qd * 4 + r;
#pragma unroll
        for (int nf = 0; nf < 8; ++nf) {
            int gc = nf * 16 + l16;
            hb[(size_t)grow * DIM + gc] = f2bf_bits(acc[nf][r] + fc_b[gc]);
        }
        float vs = accs[r] + cb;
        if (l16 < 8) su[(size_t)grow * NH + l16] = vs;
        else         sv[(size_t)grow * NH + (l16 - 8)] = vs;
    }
}

// ---------------------------------------------------------------------------
// Fused FFN v2 (r16 EXACT structure — verified 89us; all 5 schedule variants
// regressed; FINAL). r25: cat staging loads nontemporal via ext_vector u32x4
// (51MB streamed once -> keep w1b/w2b L2-resident; FETCH was 98MB vs 51MB
// logical = thrash), out stores nontemporal (scalar float is allowed).
// ---------------------------------------------------------------------------
__global__ __launch_bounds__(512, 4) void ffn_fused_kernel(
    const ushort_t* __restrict__ cat,     // [M,512] bf16
    const ushort_t* __restrict__ w1b,     // [512,512] bf16
    const float* __restrict__ b1,         // [512]
    const ushort_t* __restrict__ w2b,     // [128,512] bf16
    const float* __restrict__ b2,         // [128]
    float* __restrict__ out, int M)
{
    constexpr int BM = 128, BK = 32, PAD = 8;
    __shared__ ushort_t As[BM][BK + PAD];        // 10.2 KB
    __shared__ ushort_t Bs[128][BK + PAD];       // 10.2 KB
    __shared__ ushort_t Fs[128][128 + PAD];      // 34.8 KB

    const int t    = threadIdx.x;
    const int bm   = blockIdx.x * BM;
    const int wid  = t >> 6, lane = t & 63;
    const int wrow = wid >> 2;          // 0..1  (64-row half)
    const int wcol = wid & 3;           // 0..3  (32-col quarter)
    const int qd   = lane >> 4, l16 = lane & 15;

    // staging slots: 512 threads cover 128 rows x 4 chunks of 8 bf16 exactly
    const int sr = t >> 2, sc8 = (t & 3) * 8;

    f32x4 acc_o[4][2];
#pragma unroll
    for (int i = 0; i < 4; ++i)
#pragma unroll
        for (int j = 0; j < 2; ++j) acc_o[i][j] = (f32x4){0.f, 0.f, 0.f, 0.f};

    for (int p = 0; p < 4; ++p) {
        f32x4 acc_f[4][2];
#pragma unroll
        for (int i = 0; i < 4; ++i)
#pragma unroll
            for (int j = 0; j < 2; ++j) acc_f[i][j] = (f32x4){0.f, 0.f, 0.f, 0.f};

        // ---- stage 1: acc_f = cat[bm..bm+128] @ w1^T[p*128..p*128+128]
        for (int k0 = 0; k0 < HID; k0 += BK) {
            {
                int gr = bm + sr;
                u32x4 val = (u32x4){0u, 0u, 0u, 0u};
                if (gr < M)
                    val = __builtin_nontemporal_load(
                        (const u32x4*)(cat + (size_t)gr * HID + k0 + sc8));
                *(u32x4*)(&As[sr][sc8]) = val;
                *(u32x4*)(&Bs[sr][sc8]) =
                    *(const u32x4*)(w1b + (size_t)(p * 128 + sr) * HID + k0 + sc8);
            }
            __syncthreads();

            bf16x8 af[4], bfr[2];
#pragma unroll
            for (int mi = 0; mi < 4; ++mi)
                af[mi] = *(const bf16x8*)(&As[wrow * 64 + mi * 16 + l16][qd * 8]);
#pragma unroll
            for (int ni = 0; ni < 2; ++ni)
                bfr[ni] = *(const bf16x8*)(&Bs[wcol * 32 + ni * 16 + l16][qd * 8]);
#pragma unroll
            for (int mi = 0; mi < 4; ++mi)
#pragma unroll
                for (int ni = 0; ni < 2; ++ni)
                    acc_f[mi][ni] = __builtin_amdgcn_mfma_f32_16x16x32_bf16(
                        af[mi], bfr[ni], acc_f[mi][ni], 0, 0, 0);
            __syncthreads();
        }

        // ---- f-panel epilogue: bias + gelu -> bf16 -> Fs
#pragma unroll
        for (int mi = 0; mi < 4; ++mi) {
#pragma unroll
            for (int r = 0; r < 4; ++r) {
                int lrow = wrow * 64 + mi * 16 + qd * 4 + r;
#pragma unroll
                for (int ni = 0; ni < 2; ++ni) {
                    int lcol = wcol * 32 + ni * 16 + l16;
                    float v = acc_f[mi][ni][r] + b1[p * 128 + lcol];
                    v = 0.5f * v * (1.f + erff(v * 0.70710678118654752f));
                    Fs[lrow][lcol] = f2bf_bits(v);
                }
            }
        }
        __syncthreads();

        // ---- stage 2: acc_o += Fs @ w2^T (K-chunk = p*128 .. p*128+128)
#pragma unroll
        for (int kk = 0; kk < 4; ++kk) {
            bf16x8 af2[4], bf2[2];
#pragma unroll
            for (int mi = 0; mi < 4; ++mi)
                af2[mi] = *(const bf16x8*)(&Fs[wrow * 64 + mi * 16 + l16][kk * 32 + qd * 8]);
#pragma unroll
            for (int ni = 0; ni < 2; ++ni) {
                int col2 = wcol * 32 + ni * 16 + l16;
                bf2[ni] = *(const bf16x8*)(w2b + (size_t)col2 * HID + p * 128 + kk * 32 + qd * 8);
            }
#pragma unroll
            for (int mi = 0; mi < 4; ++mi)
#pragma unroll
                for (int ni = 0; ni < 2; ++ni)
                    acc_o[mi][ni] = __builtin_amdgcn_mfma_f32_16x16x32_bf16(
                        af2[mi], bf2[ni], acc_o[mi][ni], 0, 0, 0);
        }
        __syncthreads();   // Fs/As/Bs free for next panel
    }

    // ---- out epilogue (f32, nontemporal scalar stores)
#pragma unroll
    for (int mi = 0; mi < 4; ++mi) {
#pragma unroll
        for (int r = 0; r < 4; ++r) {
            int lrow = wrow * 64 + mi * 16 + qd * 4 + r;
            int grow = bm + lrow;
            if (grow >= M) continue;
#pragma unroll
            for (int ni = 0; ni < 2; ++ni) {
                int gc = wcol * 32 + ni * 16 + l16;
                __builtin_nontemporal_store(acc_o[mi][ni][r] + b2[gc],
                                            out + (size_t)grow * DIM + gc);
            }
        }
    }
}

// ---------------------------------------------------------------------------
// CSR chain (r24: block_scan folded into final_scan's inline bsum prefix)
// ---------------------------------------------------------------------------
__global__ __launch_bounds__(256) void block_sum_kernel(
    const int* __restrict__ cnt, int* __restrict__ bsum)
{
    const int lane = threadIdx.x & 63, wid = threadIdx.x >> 6;
    int i = blockIdx.x * 256 + threadIdx.x;
    int v = (i < NNODES) ? cnt[i] : 0;
#pragma unroll
    for (int off = 32; off >= 1; off >>= 1) v += __shfl_down(v, off, 64);
    __shared__ int ws_[4];
    if (lane == 0) ws_[wid] = v;
    __syncthreads();
    if (threadIdx.x == 0) bsum[blockIdx.x] = ws_[0] + ws_[1] + ws_[2] + ws_[3];
}

__global__ __launch_bounds__(256) void final_scan_kernel(
    const int* __restrict__ cnt, const int* __restrict__ bsum,
    int* __restrict__ rowstart)
{
    __shared__ int sb[256];
    __shared__ int ws_[4];
    __shared__ int basev;
    const int t = threadIdx.x;
    const int b = blockIdx.x;
    const int lane = t & 63, wid = t >> 6;

    // inline prefix: basev = sum(bsum[0..b-1])  (b <= 195 < 256)
    {
        int v = (t < b) ? bsum[t] : 0;
#pragma unroll
        for (int off = 32; off >= 1; off >>= 1) v += __shfl_down(v, off, 64);
        if (lane == 0) ws_[wid] = v;
        __syncthreads();
        if (t == 0) basev = ws_[0] + ws_[1] + ws_[2] + ws_[3];
        __syncthreads();
    }

    int i = b * 256 + t;
    int v = (i < NNODES) ? cnt[i] : 0;
    sb[t] = v;
    __syncthreads();
    for (int off = 1; off < 256; off <<= 1) {
        int u = (t >= off) ? sb[t - off] : 0;
        __syncthreads();
        sb[t] += u;
        __syncthreads();
    }
    if (i < NNODES) rowstart[i] = basev + sb[t] - v;   // exclusive
    if (b == 0 && t == 0) rowstart[NNODES] = NEDGES;
}

__global__ __launch_bounds__(256) void fill_csr_kernel(
    const int* __restrict__ src, const int* __restrict__ dst,
    const int* __restrict__ rowstart, int* __restrict__ cursor,
    int* __restrict__ esrc, int E)
{
    int e = blockIdx.x * 256 + threadIdx.x;
    if (e >= E) return;
    int d = dst[e];
    int pos = rowstart[d] + atomicAdd(&cursor[d], 1);
    esrc[pos] = src[e];
}

// ---------------------------------------------------------------------------
// Gather-aggregate v7 (r24): v6 (unroll-8, SGPR hoist) + nontemporal cat
// stores (cat is write-once-read-later; keep hb/su L2-resident for the
// random gather reads instead of write-allocating 51MB of cat lines).
// ---------------------------------------------------------------------------
__device__ __forceinline__ float bf_lo(uint_t v) {
    union { uint_t i; float f; } c; c.i = v << 16; return c.f;
}
__device__ __forceinline__ float bf_hi(uint_t v) {
    union { uint_t i; float f; } c; c.i = v & 0xffff0000u; return c.f;
}
__device__ __forceinline__ void st_bf2_nt(ushort_t* p, float a, float b) {
    __hip_bfloat16 ba = __float2bfloat16(a), bb = __float2bfloat16(b);
    uint_t v = (uint_t)(*(ushort_t*)&ba) | ((uint_t)(*(ushort_t*)&bb) << 16);
    __builtin_nontemporal_store(v, (uint_t*)p);
}

__global__ __launch_bounds__(256) void gather_aggregate_kernel(
    const int* __restrict__ rowstart, const int* __restrict__ esrc,
    const ushort_t* __restrict__ hb,
    const float* __restrict__ su, const float* __restrict__ sv,
    const float* __restrict__ out_deg,
    ushort_t* __restrict__ cat, int N)
{
    const int wave = threadIdx.x >> 6;
    const int lane = threadIdx.x & 63;
    const int n = blockIdx.x * 4 + wave;
    if (n >= N) return;

    const int d0 = lane << 1;          // this lane's dims {d0, d0+1}
    const int h0 = d0 & 7;             // heads {h0, h0+1} (h0 even)

    const int e0  = rowstart[n];
    const int deg = rowstart[n + 1] - e0;
    const float2 svv = *(const float2*)(sv + (size_t)n * NH + h0);
    const float od_d = out_deg[n];

    // preload edge list into registers: lane i holds esrc[e0+i] (deg<=64 case)
    int es = 0;
    if (deg > 0) es = esrc[e0 + (lane < deg ? lane : deg - 1)];

    float den0 = 0.f, den1 = 0.f;
    float m0 = 0.f, m1 = 0.f, s0 = 0.f, s1 = 0.f, n0 = 0.f, n1 = 0.f;

#define GA_LOADS(u, jj)                                                       \
    {                                                                         \
        int sv_ = ((jj) < 64) ? __shfl(es, (jj), 64) : esrc[e0 + (jj)];       \
        sX[u] = __builtin_amdgcn_readfirstlane(sv_);                          \
    }
#define GA_FETCH(u)                                                           \
    {                                                                         \
        suX[u] = *(const float2*)(su + (size_t)sX[u] * NH + h0);              \
        odX[u] = out_deg[sX[u]];                                              \
        hvX[u] = *(const uint_t*)(hb + (size_t)sX[u] * DIM + d0);             \
    }
#define GA_COMPUTE(u)                                                         \
    {                                                                         \
        float sc0 = suX[u].x + svv.x; sc0 = sc0 < 0.f ? 0.2f * sc0 : sc0;     \
        float sc1 = suX[u].y + svv.y; sc1 = sc1 < 0.f ? 0.2f * sc1 : sc1;     \
        float ex0 = __expf(sc0), ex1 = __expf(sc1);                           \
        den0 += ex0; den1 += ex1;                                             \
        float nrm = rsqrtf(odX[u] * od_d);                                    \
        float hs0 = bf_lo(hvX[u]), hs1 = bf_hi(hvX[u]);                       \
        m0 += hs0 * ex0; m1 += hs1 * ex1;                                     \
        s0 += hs0;       s1 += hs1;                                           \
        n0 += hs0 * nrm; n1 += hs1 * nrm;                                     \
    }

    int j = 0;
    const int deg8 = deg & ~7;
    for (; j < deg8; j += 8) {
        int sX[8]; float2 suX[8]; float odX[8]; uint_t hvX[8];
#pragma unroll
        for (int u = 0; u < 8; ++u) GA_LOADS(u, j + u)
#pragma unroll
        for (int u = 0; u < 8; ++u) GA_FETCH(u)
#pragma unroll
        for (int u = 0; u < 8; ++u) GA_COMPUTE(u)
    }
    if (deg & 4) {
        int sX[4]; float2 suX[4]; float odX[4]; uint_t hvX[4];
#pragma unroll
        for (int u = 0; u < 4; ++u) GA_LOADS(u, j + u)
#pragma unroll
        for (int u = 0; u < 4; ++u) GA_FETCH(u)
#pragma unroll
        for (int u = 0; u < 4; ++u) GA_COMPUTE(u)
        j += 4;
    }
    for (; j < deg; ++j) {
        int sX[1]; float2 suX[1]; float odX[1]; uint_t hvX[1];
        GA_LOADS(0, j)
        GA_FETCH(0)
        GA_COMPUTE(0)
    }
#undef GA_LOADS
#undef GA_FETCH
#undef GA_COMPUTE

    const float inv = 1.f / fmaxf((float)deg, 1.f);
    const float r0 = den0 > 0.f ? 1.f / den0 : 0.f;
    const float r1 = den1 > 0.f ? 1.f / den1 : 0.f;
    ushort_t* row = cat + (size_t)n * 512;
    __builtin_nontemporal_store(*(const uint_t*)(hb + (size_t)n * DIM + d0),
                                (uint_t*)(row + d0));
    st_bf2_nt(row + 128 + d0, m0 * r0, m1 * r1);
    st_bf2_nt(row + 256 + d0, s0 * inv, s1 * inv);
    st_bf2_nt(row + 384 + d0, n0, n1);
}

// ---------------------------------------------------------------------------
extern "C" void kernel_launch(void* const* d_in, const int* in_sizes, int n_in,
                              void* d_out, int out_size, void* d_ws, size_t ws_size,
                              hipStream_t stream)
{
    const float* x    = (const float*)d_in[0];
    const int*   src  = (const int*)d_in[1];
    const int*   dst  = (const int*)d_in[2];
    const float* fc_w = (const float*)d_in[3];
    const float* fc_b = (const float*)d_in[4];
    const float* au_w = (const float*)d_in[5];
    const float* au_b = (const float*)d_in[6];
    const float* av_w = (const float*)d_in[7];
    const float* w1   = (const float*)d_in[8];
    const float* b1   = (const float*)d_in[9];
    const float* w2   = (const float*)d_in[10];
    const float* b2   = (const float*)d_in[11];
    float* out = (float*)d_out;

    const int N = NNODES, E = NEDGES;

    // ws layout (no trailing backslashes in comments -- r6 lesson)
    char* w = (char*)d_ws;
    ushort_t* fc_wb = (ushort_t*)w;  w += (size_t)DIM * DIM * 2;
    ushort_t* w1b   = (ushort_t*)w;  w += (size_t)HID * 512 * 2;
    ushort_t* w2b   = (ushort_t*)w;  w += (size_t)DIM * HID * 2;
    ushort_t* afc   = (ushort_t*)w;  w += (size_t)16 * DIM * 2;      // 4 KB
    float* abc      = (float*)w;     w += (size_t)16 * 4;
    ushort_t* hb    = (ushort_t*)w;  w += (size_t)N * DIM * 2;       // 12.8 MB
    ushort_t* cat   = (ushort_t*)w;  w += (size_t)N * 512 * 2;       // 51.2 MB
    float* su       = (float*)w;     w += (size_t)N * NH * 4;
    float* sv       = (float*)w;     w += (size_t)N * NH * 4;
    float* out_deg  = (float*)w;     w += (size_t)N * 4;             // zeroed (1/3)
    int*   in_cnt   = (int*)w;       w += (size_t)N * 4;             // zeroed (2/3)
    int*   cursor   = (int*)w;       w += (size_t)N * 4;             // zeroed (3/3)
    int*   rowstart = (int*)w;       w += (size_t)(N + 16) * 4;
    int*   bsum     = (int*)w;       w += (size_t)256 * 4;
    int*   boff     = (int*)w;       w += (size_t)256 * 4;
    int*   esrc     = (int*)w;       w += (size_t)E * 4;             // 3.2 MB

    (void)hipMemsetAsync(out_deg, 0, (size_t)N * 3 * 4, stream);

    // 0) weights convert + composite + degree count (one dispatch)
    convert_deg_kernel<<<CVT_BLOCKS + DEG_BLOCKS, 256, 0, stream>>>(
        fc_w, fc_b, au_w, au_b, av_w, w1, w2, src, dst,
        fc_wb, w1b, w2b, afc, abc, out_deg, in_cnt, E);

    // 1+2) fused fc GEMM + attn scores (composite weights; barrier-free)
    fc_attn_kernel<<<(N / 16 + 3) / 4, 256, 0, stream>>>(
        x, fc_wb, fc_b, afc, abc, hb, su, sv, N);

    // 3) CSR: block sums -> scan(+inline prefix) -> fill
    block_sum_kernel<<<NB, 256, 0, stream>>>(in_cnt, bsum);
    final_scan_kernel<<<NB, 256, 0, stream>>>(in_cnt, bsum, rowstart);
    fill_csr_kernel<<<(E + 255) / 256, 256, 0, stream>>>(src, dst, rowstart, cursor, esrc, E);

    // 4) gather aggregation -> full bf16 cat (nontemporal cat stores)
    gather_aggregate_kernel<<<(N + 3) / 4, 256, 0, stream>>>(
        rowstart, esrc, hb, su, sv, out_deg, cat, N);

    // 5) fused FFN v2 (r16 exact, FINAL) + nontemporal cat loads/out stores
    ffn_fused_kernel<<<(N + 127) / 128, 512, 0, stream>>>(
        cat, w1b, b1, w2b, b2, out, N);
}

// Round 16
// 364.211 us; speedup vs baseline: 1.0856x; 1.0856x over previous
//
#include <hip/hip_runtime.h>
#include <hip/hip_bf16.h>

#define NNODES 50000
#define NEDGES 800000
#define DIM 128
#define NH 8
#define HID 512
#define NB 196               // scan blocks: ceil(50000/256)
#define CVT_BLOCKS 1344
#define DEG_BLOCKS 3125      // ceil(800000/256)

typedef unsigned short ushort_t;
typedef unsigned int uint_t;
typedef __attribute__((ext_vector_type(8))) short bf16x8;
typedef __attribute__((ext_vector_type(4))) float f32x4;

__device__ __forceinline__ ushort_t f2bf_bits(float v) {
    __hip_bfloat16 b = __float2bfloat16(v);
    return *(ushort_t*)&b;
}

// ---------------------------------------------------------------------------
// convert weights + attn-composite + degree_count in ONE dispatch (r24
// merge, kept). NT experiment (r25) reverted: NT cat/x loads bypassed L2 and
// cost ffn +23us (89->112) at essentially unchanged FETCH — cat lines
// freshly written by gather were L2 hits before.
// Composite (r19, verified): su = x @ (au_w@fc_w)^T + (au_b + au_w.fc_b),
// sv = x @ (av_w@fc_w)^T + (av_w.fc_b).
// ---------------------------------------------------------------------------
__global__ __launch_bounds__(256) void convert_deg_kernel(
    const float* __restrict__ fc_w, const float* __restrict__ fc_b,
    const float* __restrict__ au_w, const float* __restrict__ au_b,
    const float* __restrict__ av_w,
    const float* __restrict__ w1, const float* __restrict__ w2,
    const int* __restrict__ src, const int* __restrict__ dst,
    ushort_t* __restrict__ fc_wb, ushort_t* __restrict__ w1b,
    ushort_t* __restrict__ w2b,
    ushort_t* __restrict__ afc, float* __restrict__ abc,
    float* __restrict__ out_deg, int* __restrict__ in_cnt, int E)
{
    const int b = blockIdx.x;
    if (b >= CVT_BLOCKS) {
        int e = (b - CVT_BLOCKS) * 256 + threadIdx.x;
        if (e < E) {
            unsafeAtomicAdd(&out_deg[src[e]], 1.f);
            atomicAdd(&in_cnt[dst[e]], 1);
        }
        return;
    }

    int i = b * 256 + threadIdx.x;
    if (i < 16384)
        ((__hip_bfloat16*)fc_wb)[i] = __float2bfloat16(fc_w[i]);
    else if (i < 278528)
        ((__hip_bfloat16*)w1b)[i - 16384] = __float2bfloat16(w1[i - 16384]);
    else if (i < 344064)
        ((__hip_bfloat16*)w2b)[i - 278528] = __float2bfloat16(w2[i - 278528]);

    if (i < 2048) {
        int row = i >> 7, col = i & 127;
        const float* wrow = (row < 8) ? (au_w + row * DIM) : (av_w + (row - 8) * DIM);
        float s = 0.f;
        for (int j = 0; j < DIM; ++j) s += wrow[j] * fc_w[j * DIM + col];
        afc[row * DIM + col] = f2bf_bits(s);
    }
    if (i < 16) {
        const float* wrow = (i < 8) ? (au_w + i * DIM) : (av_w + (i - 8) * DIM);
        float s = (i < 8) ? au_b[i] : 0.f;
        for (int j = 0; j < DIM; ++j) s += wrow[j] * fc_b[j];
        abc[i] = s;
    }
}

// ---------------------------------------------------------------------------
// Fused fc + attn-scores (r19, verified; plain cached loads): barrier-free
// main loop; fc_wb + composite afc staged in LDS once; each wave owns a
// 16-row tile, 9 MFMAs per K-step.
// ---------------------------------------------------------------------------
__global__ __launch_bounds__(256, 4) void fc_attn_kernel(
    const float* __restrict__ x,
    const ushort_t* __restrict__ fc_wb, const float* __restrict__ fc_b,
    const ushort_t* __restrict__ afc, const float* __restrict__ abc,
    ushort_t* __restrict__ hb, float* __restrict__ su, float* __restrict__ sv,
    int M)
{
    constexpr int PAD = 8;
    __shared__ ushort_t Ws[128][128 + PAD];   // fc weights, [n][k]  34.8 KB
    __shared__ ushort_t Aw[16][128 + PAD];    // composite [au;av]    4.4 KB

    const int t    = threadIdx.x;
    const int wid  = t >> 6, lane = t & 63;
    const int qd   = lane >> 4, l16 = lane & 15;

#pragma unroll
    for (int i = 0; i < 8; ++i) {
        int v = t + i * 256;               // 0..2047
        int row = v >> 4, ch = v & 15;
        *(uint4*)(&Ws[row][ch * 8]) = *(const uint4*)(fc_wb + row * 128 + ch * 8);
    }
    {
        int row = t >> 4, ch = t & 15;
        *(uint4*)(&Aw[row][ch * 8]) = *(const uint4*)(afc + row * 128 + ch * 8);
    }
    __syncthreads();

    const int tile = blockIdx.x * 4 + wid;
    if (tile * 16 >= M) return;

    const int arow = tile * 16 + l16;
    const float* xp = x + (size_t)arow * DIM + qd * 8;
    const float cb = abc[l16];

    f32x4 acc[8], accs;
#pragma unroll
    for (int i = 0; i < 8; ++i) acc[i] = (f32x4){0.f, 0.f, 0.f, 0.f};
    accs = (f32x4){0.f, 0.f, 0.f, 0.f};

#pragma unroll
    for (int ks = 0; ks < 4; ++ks) {
        float4 f0 = *(const float4*)(xp + ks * 32);
        float4 f1 = *(const float4*)(xp + ks * 32 + 4);
        union { ushort_t u[8]; bf16x8 v; } a;
        a.u[0] = f2bf_bits(f0.x); a.u[1] = f2bf_bits(f0.y);
        a.u[2] = f2bf_bits(f0.z); a.u[3] = f2bf_bits(f0.w);
        a.u[4] = f2bf_bits(f1.x); a.u[5] = f2bf_bits(f1.y);
        a.u[6] = f2bf_bits(f1.z); a.u[7] = f2bf_bits(f1.w);
#pragma unroll
        for (int nf = 0; nf < 8; ++nf) {
            bf16x8 bw = *(const bf16x8*)(&Ws[nf * 16 + l16][ks * 32 + qd * 8]);
            acc[nf] = __builtin_amdgcn_mfma_f32_16x16x32_bf16(a.v, bw, acc[nf], 0, 0, 0);
        }
        bf16x8 ba = *(const bf16x8*)(&Aw[l16][ks * 32 + qd * 8]);
        accs = __builtin_amdgcn_mfma_f32_16x16x32_bf16(a.v, ba, accs, 0, 0, 0);
    }

#pragma unroll
    for (int r = 0; r < 4; ++r) {
        int grow = tile * 16 + qd * 4 + r;
#pragma unroll
        for (int nf = 0; nf < 8; ++nf) {
            int gc = nf * 16 + l16;
            hb[(size_t)grow * DIM + gc] = f2bf_bits(acc[nf][r] + fc_b[gc]);
        }
        float vs = accs[r] + cb;
        if (l16 < 8) su[(size_t)grow * NH + l16] = vs;
        else         sv[(size_t)grow * NH + (l16 - 8)] = vs;
    }
}

// ---------------------------------------------------------------------------
// Fused FFN v2 (r16 EXACT — verified 89us x5; all schedule + cache-policy
// variants regressed: BM64=129, BK64+L2-B=127, dbuf=95.5, NT-loads=112.
// FINAL. Do not re-tune.)
// ---------------------------------------------------------------------------
__global__ __launch_bounds__(512, 4) void ffn_fused_kernel(
    const ushort_t* __restrict__ cat,     // [M,512] bf16
    const ushort_t* __restrict__ w1b,     // [512,512] bf16
    const float* __restrict__ b1,         // [512]
    const ushort_t* __restrict__ w2b,     // [128,512] bf16
    const float* __restrict__ b2,         // [128]
    float* __restrict__ out, int M)
{
    constexpr int BM = 128, BK = 32, PAD = 8;
    __shared__ ushort_t As[BM][BK + PAD];        // 10.2 KB
    __shared__ ushort_t Bs[128][BK + PAD];       // 10.2 KB
    __shared__ ushort_t Fs[128][128 + PAD];      // 34.8 KB

    const int t    = threadIdx.x;
    const int bm   = blockIdx.x * BM;
    const int wid  = t >> 6, lane = t & 63;
    const int wrow = wid >> 2;          // 0..1  (64-row half)
    const int wcol = wid & 3;           // 0..3  (32-col quarter)
    const int qd   = lane >> 4, l16 = lane & 15;

    // staging slots: 512 threads cover 128 rows x 4 chunks of 8 bf16 exactly
    const int sr = t >> 2, sc8 = (t & 3) * 8;

    f32x4 acc_o[4][2];
#pragma unroll
    for (int i = 0; i < 4; ++i)
#pragma unroll
        for (int j = 0; j < 2; ++j) acc_o[i][j] = (f32x4){0.f, 0.f, 0.f, 0.f};

    for (int p = 0; p < 4; ++p) {
        f32x4 acc_f[4][2];
#pragma unroll
        for (int i = 0; i < 4; ++i)
#pragma unroll
            for (int j = 0; j < 2; ++j) acc_f[i][j] = (f32x4){0.f, 0.f, 0.f, 0.f};

        // ---- stage 1: acc_f = cat[bm..bm+128] @ w1^T[p*128..p*128+128]
        for (int k0 = 0; k0 < HID; k0 += BK) {
            {
                int gr = bm + sr;
                uint4 val = make_uint4(0u, 0u, 0u, 0u);
                if (gr < M) val = *(const uint4*)(cat + (size_t)gr * HID + k0 + sc8);
                *(uint4*)(&As[sr][sc8]) = val;
                *(uint4*)(&Bs[sr][sc8]) =
                    *(const uint4*)(w1b + (size_t)(p * 128 + sr) * HID + k0 + sc8);
            }
            __syncthreads();

            bf16x8 af[4], bfr[2];
#pragma unroll
            for (int mi = 0; mi < 4; ++mi)
                af[mi] = *(const bf16x8*)(&As[wrow * 64 + mi * 16 + l16][qd * 8]);
#pragma unroll
            for (int ni = 0; ni < 2; ++ni)
                bfr[ni] = *(const bf16x8*)(&Bs[wcol * 32 + ni * 16 + l16][qd * 8]);
#pragma unroll
            for (int mi = 0; mi < 4; ++mi)
#pragma unroll
                for (int ni = 0; ni < 2; ++ni)
                    acc_f[mi][ni] = __builtin_amdgcn_mfma_f32_16x16x32_bf16(
                        af[mi], bfr[ni], acc_f[mi][ni], 0, 0, 0);
            __syncthreads();
        }

        // ---- f-panel epilogue: bias + gelu -> bf16 -> Fs
#pragma unroll
        for (int mi = 0; mi < 4; ++mi) {
#pragma unroll
            for (int r = 0; r < 4; ++r) {
                int lrow = wrow * 64 + mi * 16 + qd * 4 + r;
#pragma unroll
                for (int ni = 0; ni < 2; ++ni) {
                    int lcol = wcol * 32 + ni * 16 + l16;
                    float v = acc_f[mi][ni][r] + b1[p * 128 + lcol];
                    v = 0.5f * v * (1.f + erff(v * 0.70710678118654752f));
                    Fs[lrow][lcol] = f2bf_bits(v);
                }
            }
        }
        __syncthreads();

        // ---- stage 2: acc_o += Fs @ w2^T (K-chunk = p*128 .. p*128+128)
#pragma unroll
        for (int kk = 0; kk < 4; ++kk) {
            bf16x8 af2[4], bf2[2];
#pragma unroll
            for (int mi = 0; mi < 4; ++mi)
                af2[mi] = *(const bf16x8*)(&Fs[wrow * 64 + mi * 16 + l16][kk * 32 + qd * 8]);
#pragma unroll
            for (int ni = 0; ni < 2; ++ni) {
                int col2 = wcol * 32 + ni * 16 + l16;
                bf2[ni] = *(const bf16x8*)(w2b + (size_t)col2 * HID + p * 128 + kk * 32 + qd * 8);
            }
#pragma unroll
            for (int mi = 0; mi < 4; ++mi)
#pragma unroll
                for (int ni = 0; ni < 2; ++ni)
                    acc_o[mi][ni] = __builtin_amdgcn_mfma_f32_16x16x32_bf16(
                        af2[mi], bf2[ni], acc_o[mi][ni], 0, 0, 0);
        }
        __syncthreads();   // Fs/As/Bs free for next panel
    }

    // ---- out epilogue (f32)
#pragma unroll
    for (int mi = 0; mi < 4; ++mi) {
#pragma unroll
        for (int r = 0; r < 4; ++r) {
            int lrow = wrow * 64 + mi * 16 + qd * 4 + r;
            int grow = bm + lrow;
            if (grow >= M) continue;
#pragma unroll
            for (int ni = 0; ni < 2; ++ni) {
                int gc = wcol * 32 + ni * 16 + l16;
                out[(size_t)grow * DIM + gc] = acc_o[mi][ni][r] + b2[gc];
            }
        }
    }
}

// ---------------------------------------------------------------------------
// CSR chain (block_scan folded into final_scan's inline bsum prefix)
// ---------------------------------------------------------------------------
__global__ __launch_bounds__(256) void block_sum_kernel(
    const int* __restrict__ cnt, int* __restrict__ bsum)
{
    const int lane = threadIdx.x & 63, wid = threadIdx.x >> 6;
    int i = blockIdx.x * 256 + threadIdx.x;
    int v = (i < NNODES) ? cnt[i] : 0;
#pragma unroll
    for (int off = 32; off >= 1; off >>= 1) v += __shfl_down(v, off, 64);
    __shared__ int ws_[4];
    if (lane == 0) ws_[wid] = v;
    __syncthreads();
    if (threadIdx.x == 0) bsum[blockIdx.x] = ws_[0] + ws_[1] + ws_[2] + ws_[3];
}

__global__ __launch_bounds__(256) void final_scan_kernel(
    const int* __restrict__ cnt, const int* __restrict__ bsum,
    int* __restrict__ rowstart)
{
    __shared__ int sb[256];
    __shared__ int ws_[4];
    __shared__ int basev;
    const int t = threadIdx.x;
    const int b = blockIdx.x;
    const int lane = t & 63, wid = t >> 6;

    // inline prefix: basev = sum(bsum[0..b-1])  (b <= 195 < 256)
    {
        int v = (t < b) ? bsum[t] : 0;
#pragma unroll
        for (int off = 32; off >= 1; off >>= 1) v += __shfl_down(v, off, 64);
        if (lane == 0) ws_[wid] = v;
        __syncthreads();
        if (t == 0) basev = ws_[0] + ws_[1] + ws_[2] + ws_[3];
        __syncthreads();
    }

    int i = b * 256 + t;
    int v = (i < NNODES) ? cnt[i] : 0;
    sb[t] = v;
    __syncthreads();
    for (int off = 1; off < 256; off <<= 1) {
        int u = (t >= off) ? sb[t - off] : 0;
        __syncthreads();
        sb[t] += u;
        __syncthreads();
    }
    if (i < NNODES) rowstart[i] = basev + sb[t] - v;   // exclusive
    if (b == 0 && t == 0) rowstart[NNODES] = NEDGES;
}

__global__ __launch_bounds__(256) void fill_csr_kernel(
    const int* __restrict__ src, const int* __restrict__ dst,
    const int* __restrict__ rowstart, int* __restrict__ cursor,
    int* __restrict__ esrc, int E)
{
    int e = blockIdx.x * 256 + threadIdx.x;
    if (e >= E) return;
    int d = dst[e];
    int pos = rowstart[d] + atomicAdd(&cursor[d], 1);
    esrc[pos] = src[e];
}

// ---------------------------------------------------------------------------
// Gather-aggregate (r23, verified: unroll-8 + SGPR hoist; plain cached
// stores — NT reverted).
// ---------------------------------------------------------------------------
__device__ __forceinline__ float bf_lo(uint_t v) {
    union { uint_t i; float f; } c; c.i = v << 16; return c.f;
}
__device__ __forceinline__ float bf_hi(uint_t v) {
    union { uint_t i; float f; } c; c.i = v & 0xffff0000u; return c.f;
}
__device__ __forceinline__ void st_bf2(ushort_t* p, float a, float b) {
    __hip_bfloat16 ba = __float2bfloat16(a), bb = __float2bfloat16(b);
    uint_t v = (uint_t)(*(ushort_t*)&ba) | ((uint_t)(*(ushort_t*)&bb) << 16);
    *(uint_t*)p = v;
}

__global__ __launch_bounds__(256) void gather_aggregate_kernel(
    const int* __restrict__ rowstart, const int* __restrict__ esrc,
    const ushort_t* __restrict__ hb,
    const float* __restrict__ su, const float* __restrict__ sv,
    const float* __restrict__ out_deg,
    ushort_t* __restrict__ cat, int N)
{
    const int wave = threadIdx.x >> 6;
    const int lane = threadIdx.x & 63;
    const int n = blockIdx.x * 4 + wave;
    if (n >= N) return;

    const int d0 = lane << 1;          // this lane's dims {d0, d0+1}
    const int h0 = d0 & 7;             // heads {h0, h0+1} (h0 even)

    const int e0  = rowstart[n];
    const int deg = rowstart[n + 1] - e0;
    const float2 svv = *(const float2*)(sv + (size_t)n * NH + h0);
    const float od_d = out_deg[n];

    // preload edge list into registers: lane i holds esrc[e0+i] (deg<=64 case)
    int es = 0;
    if (deg > 0) es = esrc[e0 + (lane < deg ? lane : deg - 1)];

    float den0 = 0.f, den1 = 0.f;
    float m0 = 0.f, m1 = 0.f, s0 = 0.f, s1 = 0.f, n0 = 0.f, n1 = 0.f;

#define GA_LOADS(u, jj)                                                       \
    {                                                                         \
        int sv_ = ((jj) < 64) ? __shfl(es, (jj), 64) : esrc[e0 + (jj)];       \
        sX[u] = __builtin_amdgcn_readfirstlane(sv_);                          \
    }
#define GA_FETCH(u)                                                           \
    {                                                                         \
        suX[u] = *(const float2*)(su + (size_t)sX[u] * NH + h0);              \
        odX[u] = out_deg[sX[u]];                                              \
        hvX[u] = *(const uint_t*)(hb + (size_t)sX[u] * DIM + d0);             \
    }
#define GA_COMPUTE(u)                                                         \
    {                                                                         \
        float sc0 = suX[u].x + svv.x; sc0 = sc0 < 0.f ? 0.2f * sc0 : sc0;     \
        float sc1 = suX[u].y + svv.y; sc1 = sc1 < 0.f ? 0.2f * sc1 : sc1;     \
        float ex0 = __expf(sc0), ex1 = __expf(sc1);                           \
        den0 += ex0; den1 += ex1;                                             \
        float nrm = rsqrtf(odX[u] * od_d);                                    \
        float hs0 = bf_lo(hvX[u]), hs1 = bf_hi(hvX[u]);                       \
        m0 += hs0 * ex0; m1 += hs1 * ex1;                                     \
        s0 += hs0;       s1 += hs1;                                           \
        n0 += hs0 * nrm; n1 += hs1 * nrm;                                     \
    }

    int j = 0;
    const int deg8 = deg & ~7;
    for (; j < deg8; j += 8) {
        int sX[8]; float2 suX[8]; float odX[8]; uint_t hvX[8];
#pragma unroll
        for (int u = 0; u < 8; ++u) GA_LOADS(u, j + u)
#pragma unroll
        for (int u = 0; u < 8; ++u) GA_FETCH(u)
#pragma unroll
        for (int u = 0; u < 8; ++u) GA_COMPUTE(u)
    }
    if (deg & 4) {
        int sX[4]; float2 suX[4]; float odX[4]; uint_t hvX[4];
#pragma unroll
        for (int u = 0; u < 4; ++u) GA_LOADS(u, j + u)
#pragma unroll
        for (int u = 0; u < 4; ++u) GA_FETCH(u)
#pragma unroll
        for (int u = 0; u < 4; ++u) GA_COMPUTE(u)
        j += 4;
    }
    for (; j < deg; ++j) {
        int sX[1]; float2 suX[1]; float odX[1]; uint_t hvX[1];
        GA_LOADS(0, j)
        GA_FETCH(0)
        GA_COMPUTE(0)
    }
#undef GA_LOADS
#undef GA_FETCH
#undef GA_COMPUTE

    const float inv = 1.f / fmaxf((float)deg, 1.f);
    const float r0 = den0 > 0.f ? 1.f / den0 : 0.f;
    const float r1 = den1 > 0.f ? 1.f / den1 : 0.f;
    ushort_t* row = cat + (size_t)n * 512;
    *(uint_t*)(row + d0) = *(const uint_t*)(hb + (size_t)n * DIM + d0);
    st_bf2(row + 128 + d0, m0 * r0, m1 * r1);
    st_bf2(row + 256 + d0, s0 * inv, s1 * inv);
    st_bf2(row + 384 + d0, n0, n1);
}

// ---------------------------------------------------------------------------
extern "C" void kernel_launch(void* const* d_in, const int* in_sizes, int n_in,
                              void* d_out, int out_size, void* d_ws, size_t ws_size,
                              hipStream_t stream)
{
    const float* x    = (const float*)d_in[0];
    const int*   src  = (const int*)d_in[1];
    const int*   dst  = (const int*)d_in[2];
    const float* fc_w = (const float*)d_in[3];
    const float* fc_b = (const float*)d_in[4];
    const float* au_w = (const float*)d_in[5];
    const float* au_b = (const float*)d_in[6];
    const float* av_w = (const float*)d_in[7];
    const float* w1   = (const float*)d_in[8];
    const float* b1   = (const float*)d_in[9];
    const float* w2   = (const float*)d_in[10];
    const float* b2   = (const float*)d_in[11];
    float* out = (float*)d_out;

    const int N = NNODES, E = NEDGES;

    // ws layout (no trailing backslashes in comments -- r6 lesson)
    char* w = (char*)d_ws;
    ushort_t* fc_wb = (ushort_t*)w;  w += (size_t)DIM * DIM * 2;
    ushort_t* w1b   = (ushort_t*)w;  w += (size_t)HID * 512 * 2;
    ushort_t* w2b   = (ushort_t*)w;  w += (size_t)DIM * HID * 2;
    ushort_t* afc   = (ushort_t*)w;  w += (size_t)16 * DIM * 2;      // 4 KB
    float* abc      = (float*)w;     w += (size_t)16 * 4;
    ushort_t* hb    = (ushort_t*)w;  w += (size_t)N * DIM * 2;       // 12.8 MB
    ushort_t* cat   = (ushort_t*)w;  w += (size_t)N * 512 * 2;       // 51.2 MB
    float* su       = (float*)w;     w += (size_t)N * NH * 4;
    float* sv       = (float*)w;     w += (size_t)N * NH * 4;
    float* out_deg  = (float*)w;     w += (size_t)N * 4;             // zeroed (1/3)
    int*   in_cnt   = (int*)w;       w += (size_t)N * 4;             // zeroed (2/3)
    int*   cursor   = (int*)w;       w += (size_t)N * 4;             // zeroed (3/3)
    int*   rowstart = (int*)w;       w += (size_t)(N + 16) * 4;
    int*   bsum     = (int*)w;       w += (size_t)256 * 4;
    int*   boff     = (int*)w;       w += (size_t)256 * 4;
    int*   esrc     = (int*)w;       w += (size_t)E * 4;             // 3.2 MB

    (void)hipMemsetAsync(out_deg, 0, (size_t)N * 3 * 4, stream);

    // 0) weights convert + composite + degree count (one dispatch)
    convert_deg_kernel<<<CVT_BLOCKS + DEG_BLOCKS, 256, 0, stream>>>(
        fc_w, fc_b, au_w, au_b, av_w, w1, w2, src, dst,
        fc_wb, w1b, w2b, afc, abc, out_deg, in_cnt, E);

    // 1+2) fused fc GEMM + attn scores (composite weights; barrier-free)
    fc_attn_kernel<<<(N / 16 + 3) / 4, 256, 0, stream>>>(
        x, fc_wb, fc_b, afc, abc, hb, su, sv, N);

    // 3) CSR: block sums -> scan(+inline prefix) -> fill
    block_sum_kernel<<<NB, 256, 0, stream>>>(in_cnt, bsum);
    final_scan_kernel<<<NB, 256, 0, stream>>>(in_cnt, bsum, rowstart);
    fill_csr_kernel<<<(E + 255) / 256, 256, 0, stream>>>(src, dst, rowstart, cursor, esrc, E);

    // 4) gather aggregation -> full bf16 cat (unroll-8, SGPR-hoisted)
    gather_aggregate_kernel<<<(N + 3) / 4, 256, 0, stream>>>(
        rowstart, esrc, hb, su, sv, out_deg, cat, N);

    // 5) fused FFN v2 (r16 exact, FINAL)
    ffn_fused_kernel<<<(N + 127) / 128, 512, 0, stream>>>(
        cat, w1b, b1, w2b, b2, out, N);
}